// Round 1
// 1166.002 us; speedup vs baseline: 1.7289x; 1.7289x over previous
//
#include <hip/hip_runtime.h>
#include <math.h>

#define T_    2048
#define H_    2048
#define NH_   16
#define NKV_  4
#define HD_   128
#define I_    1024
#define E_    16
#define QKVN  3072
#define EPS_  1e-5f

typedef __attribute__((ext_vector_type(8))) __bf16 bf16x8;
typedef __attribute__((ext_vector_type(4))) __bf16 bf16x4;
typedef __attribute__((ext_vector_type(4))) float f32x4;
typedef __attribute__((ext_vector_type(8))) unsigned short ushort8v;
typedef __attribute__((ext_vector_type(4))) unsigned short ushort4v;

__device__ __forceinline__ unsigned short f2bf(float f) {
  union { float f; unsigned u; } v; v.f = f;
  return (unsigned short)((v.u + 0x7fffu + ((v.u >> 16) & 1u)) >> 16);
}
__device__ __forceinline__ float bf2f(unsigned short h) {
  union { unsigned u; float f; } v; v.u = ((unsigned)h) << 16;
  return v.f;
}
__device__ __forceinline__ void ldsdma16(const void* g, void* l) {
  __builtin_amdgcn_global_load_lds((const __attribute__((address_space(1))) void*)g,
                                   (__attribute__((address_space(3))) void*)l, 16, 0, 0);
}

// ---------------- RMSNorm -> bf16 ----------------
__global__ __launch_bounds__(256) void rmsnorm_bf_k(const float* __restrict__ x,
                                                    const float* __restrict__ w,
                                                    unsigned short* __restrict__ out) {
  int t = blockIdx.x;
  const float* xr = x + (size_t)t * H_;
  float ss = 0.f;
  for (int c = threadIdx.x; c < H_; c += 256) { float v = xr[c]; ss += v * v; }
#pragma unroll
  for (int off = 32; off > 0; off >>= 1) ss += __shfl_xor(ss, off);
  __shared__ float wsum[4];
  __shared__ float srstd;
  int wid = threadIdx.x >> 6;
  if ((threadIdx.x & 63) == 0) wsum[wid] = ss;
  __syncthreads();
  if (threadIdx.x == 0) {
    float tot = wsum[0] + wsum[1] + wsum[2] + wsum[3];
    srstd = rsqrtf(tot * (1.f / H_) + EPS_);
  }
  __syncthreads();
  float r = srstd;
  unsigned short* orow = out + (size_t)t * H_;
  for (int c = threadIdx.x; c < H_; c += 256) orow[c] = f2bf(xr[c] * r * w[c]);
}

// ---------------- transpose + fp32->bf16:  in[K][N] -> out[N][K] ----------------
__global__ __launch_bounds__(256) void transp_bf_k(const float* __restrict__ in,
                                                   unsigned short* __restrict__ out,
                                                   int K, int N) {
  __shared__ float tile[32][33];
  int k0 = blockIdx.y * 32, n0 = blockIdx.x * 32;
  int c = threadIdx.x & 31, r = threadIdx.x >> 5;  // r: 0..7
  for (int rr = r; rr < 32; rr += 8)
    tile[rr][c] = in[(size_t)(k0 + rr) * N + n0 + c];
  __syncthreads();
  for (int rr = r; rr < 32; rr += 8)
    out[(size_t)(n0 + rr) * K + k0 + c] = f2bf(tile[c][rr]);
}

// ---------------- MFMA GEMM: C[M,N] = A[M,K](bf16) @ Bt[N,K](bf16)^T ----------------
#define BM 128
#define BN 128
#define BK 32
__global__ __launch_bounds__(256) void gemm_mfma_tn(const unsigned short* __restrict__ A,
                                                    const unsigned short* __restrict__ Bt,
                                                    float* __restrict__ C,
                                                    int M, int N, int K) {
  __shared__ unsigned short sA[BM * BK];
  __shared__ unsigned short sB[BN * BK];
  const int tid = threadIdx.x;
  const int wave = tid >> 6;
  const int lane = tid & 63;
  const int m0 = blockIdx.y * BM;
  const int n0 = blockIdx.x * BN;
  const int wm = (wave & 1) * 64;
  const int wn = (wave >> 1) * 64;
  const int srow = wave * 32 + (lane >> 2);
  const int sch  = (lane & 3) * 8;
  const unsigned short* ga0 = A  + (size_t)(m0 + srow) * K + sch;
  const unsigned short* ga1 = A  + (size_t)(m0 + srow + 16) * K + sch;
  const unsigned short* gb0 = Bt + (size_t)(n0 + srow) * K + sch;
  const unsigned short* gb1 = Bt + (size_t)(n0 + srow + 16) * K + sch;
  unsigned short* la0 = &sA[(wave * 32) * BK];
  unsigned short* la1 = &sA[(wave * 32 + 16) * BK];
  unsigned short* lb0 = &sB[(wave * 32) * BK];
  unsigned short* lb1 = &sB[(wave * 32 + 16) * BK];
  const int frm = lane & 15;
  const int quad = lane >> 4;
  f32x4 acc[4][4] = {};
  for (int k0 = 0; k0 < K; k0 += BK) {
    ldsdma16(ga0, la0);
    ldsdma16(ga1, la1);
    ldsdma16(gb0, lb0);
    ldsdma16(gb1, lb1);
    ga0 += BK; ga1 += BK; gb0 += BK; gb1 += BK;
    __syncthreads();
    bf16x8 af[4], bf[4];
#pragma unroll
    for (int i = 0; i < 4; ++i) {
      af[i] = *(const bf16x8*)&sA[(wm + i * 16 + frm) * BK + quad * 8];
      bf[i] = *(const bf16x8*)&sB[(wn + i * 16 + frm) * BK + quad * 8];
    }
#pragma unroll
    for (int i = 0; i < 4; ++i)
#pragma unroll
      for (int j = 0; j < 4; ++j)
        acc[i][j] = __builtin_amdgcn_mfma_f32_16x16x32_bf16(af[i], bf[j], acc[i][j], 0, 0, 0);
    __syncthreads();
  }
#pragma unroll
  for (int i = 0; i < 4; ++i) {
    int rbase = m0 + wm + i * 16 + quad * 4;
#pragma unroll
    for (int j = 0; j < 4; ++j) {
      int c = n0 + wn + j * 16 + frm;
      float* cp = C + (size_t)rbase * N + c;
#pragma unroll
      for (int r = 0; r < 4; ++r) cp[(size_t)r * N] = acc[i][j][r];
    }
  }
}

// ------- routed MFMA GEMM: C[r][n] = A[gather[r]] . B_e[n][:K]; B fp32 staged->bf16 -------
__global__ __launch_bounds__(256) void gemm_mfma_routed(const unsigned short* __restrict__ A, int lda,
                                                        const float* __restrict__ B,
                                                        float* __restrict__ C, int ldc,
                                                        const int* __restrict__ gather,
                                                        const int* __restrict__ offsets,
                                                        int N, int K) {
  const int e = blockIdx.z;
  const int rs = offsets[e], re = offsets[e + 1];
  const int r0 = rs + blockIdx.y * BM;
  if (r0 >= re) return;
  const int n0 = blockIdx.x * BN;
  const float* Be = B + (size_t)e * N * K;
  __shared__ unsigned short sA[BM * BK];
  __shared__ unsigned short sB[BN * BK];
  const int tid = threadIdx.x;
  const int wave = tid >> 6;
  const int lane = tid & 63;
  const int wm = (wave & 1) * 64;
  const int wn = (wave >> 1) * 64;
  int ra0 = r0 + wave * 32 + (lane >> 2);
  int ra1 = ra0 + 16;
  int c0 = ra0 < re ? ra0 : re - 1;
  int c1 = ra1 < re ? ra1 : re - 1;
  int src0 = gather ? gather[c0] : c0;
  int src1 = gather ? gather[c1] : c1;
  const int sch = (lane & 3) * 8;
  const unsigned short* ga0 = A + (size_t)src0 * lda + sch;
  const unsigned short* ga1 = A + (size_t)src1 * lda + sch;
  unsigned short* la0 = &sA[(wave * 32) * BK];
  unsigned short* la1 = &sA[(wave * 32 + 16) * BK];
  const int brow = tid >> 1;
  const int bk = (tid & 1) * 16;
  const float* bp0 = Be + (size_t)(n0 + brow) * K + bk;
  unsigned short* bdst = &sB[brow * BK + bk];
  const int frm = lane & 15;
  const int quad = lane >> 4;
  f32x4 acc[4][4] = {};
  for (int k0 = 0; k0 < K; k0 += BK) {
    ldsdma16(ga0, la0);
    ldsdma16(ga1, la1);
    ga0 += BK; ga1 += BK;
    const float* bp = bp0 + k0;
#pragma unroll
    for (int q = 0; q < 4; ++q) {
      float4 v = *(const float4*)(bp + q * 4);
      bdst[q * 4 + 0] = f2bf(v.x);
      bdst[q * 4 + 1] = f2bf(v.y);
      bdst[q * 4 + 2] = f2bf(v.z);
      bdst[q * 4 + 3] = f2bf(v.w);
    }
    __syncthreads();
    bf16x8 af[4], bfr[4];
#pragma unroll
    for (int i = 0; i < 4; ++i) {
      af[i]  = *(const bf16x8*)&sA[(wm + i * 16 + frm) * BK + quad * 8];
      bfr[i] = *(const bf16x8*)&sB[(wn + i * 16 + frm) * BK + quad * 8];
    }
#pragma unroll
    for (int i = 0; i < 4; ++i)
#pragma unroll
      for (int j = 0; j < 4; ++j)
        acc[i][j] = __builtin_amdgcn_mfma_f32_16x16x32_bf16(af[i], bfr[j], acc[i][j], 0, 0, 0);
    __syncthreads();
  }
#pragma unroll
  for (int i = 0; i < 4; ++i) {
    int rbase = r0 + wm + i * 16 + quad * 4;
#pragma unroll
    for (int j = 0; j < 4; ++j) {
      int c = n0 + wn + j * 16 + frm;
#pragma unroll
      for (int r = 0; r < 4; ++r) {
        int rr = rbase + r;
        if (rr < re) C[(size_t)rr * ldc + c] = acc[i][j][r];
      }
    }
  }
}

// ---------------- RoPE (NeoX) in-place on q and k inside qkv ----------------
__global__ __launch_bounds__(256) void rope_k(float* __restrict__ qkv) {
  int idx = blockIdx.x * 256 + threadIdx.x;
  const int total = T_ * (NH_ + NKV_) * 64;
  if (idx >= total) return;
  int i = idx & 63;
  int head = (idx >> 6) % (NH_ + NKV_);
  int t = idx / (64 * (NH_ + NKV_));
  float* base = qkv + (size_t)t * QKVN + (head < NH_ ? head * HD_ : NH_ * HD_ + (head - NH_) * HD_);
  float inv = powf(10000.f, -(float)i * (1.f / 64.f));
  float ang = (float)t * inv;
  float c = cosf(ang), s = sinf(ang);
  float x1 = base[i], x2 = base[i + 64];
  base[i]      = x1 * c - x2 * s;
  base[i + 64] = x2 * c + x1 * s;
}

// ---------------- MFMA flash attention ----------------
// block = 256 threads = 4 waves; wave w owns 16 q-rows (q0 = qt*64 + w*16).
// KV tiles of 32 rows staged in LDS:
//   sK  [32][128] bf16, XOR-swizzled: byte ^= ((kv&7)<<4)   (kills the D=128 16-way conflict)
//   sVt [128][32] bf16 (transposed), byte ^= (((d>>2)&3)<<4) (spreads scalar staging writes)
// Q held in registers (4 bf16x8 A-fragments / lane). S, m, l, O accum in fp32.
// P converted to bf16 via a per-wave stride-36 LDS tile (conflict-free writes,
// bank-floor reads) to go from MFMA C-layout to A-layout.
__global__ __launch_bounds__(256) void flash_attn_mfma_k(const float* __restrict__ qkv,
                                                         unsigned short* __restrict__ out) {
  const int h   = blockIdx.x;
  const int qt  = (T_ / 64 - 1) - blockIdx.y;   // longest-running blocks launch first
  const int kvh = h >> 2;
  const int tid = threadIdx.x;
  const int wave = tid >> 6, lane = tid & 63;
  const int frm = lane & 15, quad = lane >> 4;
  const int q0w = qt * 64 + wave * 16;

  __shared__ unsigned short sK[32 * 128];
  __shared__ unsigned short sVt[128 * 32];
  __shared__ unsigned short sP[4][16 * 36];

  const float scale = 0.08838834764831845f;  // 1/sqrt(128)

  // ---- hoist Q into registers: qf[ks] = A-frag, row q0w+frm, d = ks*32+quad*8+j ----
  bf16x8 qf[4];
  {
    const float* qrow = qkv + (size_t)(q0w + frm) * QKVN + h * HD_;
#pragma unroll
    for (int ks = 0; ks < 4; ++ks) {
      float4 u = *(const float4*)(qrow + ks * 32 + quad * 8);
      float4 v = *(const float4*)(qrow + ks * 32 + quad * 8 + 4);
      union { ushort8v u; bf16x8 b; } cv;
      cv.u[0] = f2bf(u.x); cv.u[1] = f2bf(u.y); cv.u[2] = f2bf(u.z); cv.u[3] = f2bf(u.w);
      cv.u[4] = f2bf(v.x); cv.u[5] = f2bf(v.y); cv.u[6] = f2bf(v.z); cv.u[7] = f2bf(v.w);
      qf[ks] = cv.b;
    }
  }

  float m[4] = {-INFINITY, -INFINITY, -INFINITY, -INFINITY};
  float l[4] = {0.f, 0.f, 0.f, 0.f};
  f32x4 oacc[8] = {};

  const int srow = tid >> 3;   // 0..31  (kv row this thread stages)
  const int sc8  = tid & 7;    // 0..7   (d-chunk group)
  const int nt   = 2 * qt + 2; // kv tiles (32 rows each) through qt*64+63

  for (int kt = 0; kt < nt; ++kt) {
    const int s0 = kt * 32;
    // ---------- stage K and V^T (fp32 global -> bf16 LDS) ----------
    {
      const float* krow = qkv + (size_t)(s0 + srow) * QKVN + NH_ * HD_ + kvh * HD_;
      const float* vrow = krow + NKV_ * HD_;
#pragma unroll
      for (int c = 0; c < 4; ++c) {
        const int d0 = sc8 * 4 + c * 32;
        float4 kv4 = *(const float4*)(krow + d0);
        float4 vv4 = *(const float4*)(vrow + d0);
        ushort4v kw;
        kw[0] = f2bf(kv4.x); kw[1] = f2bf(kv4.y); kw[2] = f2bf(kv4.z); kw[3] = f2bf(kv4.w);
        unsigned koff = ((unsigned)(srow * 256 + d0 * 2)) ^ ((unsigned)(srow & 7) << 4);
        *(ushort4v*)((char*)sK + koff) = kw;
        float vv[4] = {vv4.x, vv4.y, vv4.z, vv4.w};
#pragma unroll
        for (int j = 0; j < 4; ++j) {
          const unsigned d = d0 + j;
          unsigned voff = (d * 64u + (unsigned)srow * 2u) ^ (((d >> 2) & 3u) << 4);
          *(unsigned short*)((char*)sVt + voff) = f2bf(vv[j]);
        }
      }
    }
    __syncthreads();

    if (s0 <= q0w + 15) {   // wave-uniform: skip fully-masked tiles
      // ---------- S = Q K^T  (2 kj-subtiles x 4 k-slices) ----------
      f32x4 sacc[2] = {};
#pragma unroll
      for (int sub = 0; sub < 2; ++sub) {
        const int row = sub * 16 + frm;
        const unsigned swz = (unsigned)(row & 7) << 4;
#pragma unroll
        for (int ks = 0; ks < 4; ++ks) {
          unsigned koff = ((unsigned)(row * 256 + (ks * 32 + quad * 8) * 2)) ^ swz;
          bf16x8 kf = *(const bf16x8*)((char*)sK + koff);
          sacc[sub] = __builtin_amdgcn_mfma_f32_16x16x32_bf16(qf[ks], kf, sacc[sub], 0, 0, 0);
        }
      }
      const bool edge = (s0 + 31 > q0w);
      unsigned short* sPw = sP[wave];
      // ---------- online softmax (fp32, row stats across frm lanes) ----------
#pragma unroll
      for (int r = 0; r < 4; ++r) {
        float s0v = sacc[0][r] * scale;
        float s1v = sacc[1][r] * scale;
        const int qi = q0w + quad * 4 + r;
        if (edge) {
          if (s0 + frm > qi)      s0v = -INFINITY;
          if (s0 + 16 + frm > qi) s1v = -INFINITY;
        }
        float mx = fmaxf(s0v, s1v);
        mx = fmaxf(mx, __shfl_xor(mx, 1));
        mx = fmaxf(mx, __shfl_xor(mx, 2));
        mx = fmaxf(mx, __shfl_xor(mx, 4));
        mx = fmaxf(mx, __shfl_xor(mx, 8));
        const float mnew = fmaxf(m[r], mx);
        const float p0 = __expf(s0v - mnew);
        const float p1 = __expf(s1v - mnew);
        float rs = p0 + p1;
        rs += __shfl_xor(rs, 1);
        rs += __shfl_xor(rs, 2);
        rs += __shfl_xor(rs, 4);
        rs += __shfl_xor(rs, 8);
        const float alpha = __expf(m[r] - mnew);
        l[r] = l[r] * alpha + rs;
        m[r] = mnew;
        sPw[(quad * 4 + r) * 36 + frm]      = f2bf(p0);
        sPw[(quad * 4 + r) * 36 + frm + 16] = f2bf(p1);
#pragma unroll
        for (int dt = 0; dt < 8; ++dt) oacc[dt][r] *= alpha;
      }
      // ---------- PV: O += P @ V  (P via LDS layout flip, V^T fragments) ----------
      bf16x4 plo = *(const bf16x4*)&sPw[frm * 36 + quad * 8];
      bf16x4 phi = *(const bf16x4*)&sPw[frm * 36 + quad * 8 + 4];
      bf16x8 pa = __builtin_shufflevector(plo, phi, 0, 1, 2, 3, 4, 5, 6, 7);
#pragma unroll
      for (int dt = 0; dt < 8; ++dt) {
        const unsigned drow = dt * 16 + frm;
        unsigned voff = (drow * 64u + (unsigned)quad * 16u) ^ (((drow >> 2) & 3u) << 4);
        bf16x8 vf = *(const bf16x8*)((char*)sVt + voff);
        oacc[dt] = __builtin_amdgcn_mfma_f32_16x16x32_bf16(pa, vf, oacc[dt], 0, 0, 0);
      }
    }
    __syncthreads();
  }

  // ---------- epilogue: O / l -> bf16 out ----------
#pragma unroll
  for (int r = 0; r < 4; ++r) {
    const float linv = 1.f / l[r];
    const int row = q0w + quad * 4 + r;
    unsigned short* orow = out + (size_t)row * (NH_ * HD_) + h * HD_;
#pragma unroll
    for (int dt = 0; dt < 8; ++dt)
      orow[dt * 16 + frm] = f2bf(oacc[dt][r] * linv);
  }
}

// ---------------- elementwise ----------------
__global__ __launch_bounds__(256) void add_k(const float* __restrict__ a, float* __restrict__ b, int n) {
  int idx = blockIdx.x * 256 + threadIdx.x;
  if (idx < n) b[idx] = a[idx] + b[idx];
}

__global__ __launch_bounds__(256) void silu_mul_bf_k(const float* __restrict__ in,
                                                     unsigned short* __restrict__ out,
                                                     int rows, int n) {
  int idx = blockIdx.x * 256 + threadIdx.x;
  if (idx >= rows * n) return;
  int r = idx / n, c = idx - r * n;
  float g = in[(size_t)r * 2 * n + c];
  float u = in[(size_t)r * 2 * n + n + c];
  out[(size_t)r * n + c] = f2bf((g / (1.f + expf(-g))) * u);
}

// ---------- gate logits, full fp32 path: inline rmsnorm(hidden, ln_post_w) . gate_w ----------
// Routing is discontinuous (top-2 argmax) — must NOT see bf16-rounded inputs.
__global__ __launch_bounds__(256) void gate_fp32_k(const float* __restrict__ hidden,
                                                   const float* __restrict__ lnw,
                                                   const float* __restrict__ gw,
                                                   float* __restrict__ logits) {
  int t = blockIdx.x;
  const float* xr = hidden + (size_t)t * H_;
  float ss = 0.f;
  for (int c = threadIdx.x; c < H_; c += 256) { float v = xr[c]; ss += v * v; }
#pragma unroll
  for (int off = 32; off > 0; off >>= 1) ss += __shfl_xor(ss, off);
  __shared__ float wsum[4];
  __shared__ float srstd;
  int wid = threadIdx.x >> 6;
  if ((threadIdx.x & 63) == 0) wsum[wid] = ss;
  __syncthreads();
  if (threadIdx.x == 0) {
    float tot = wsum[0] + wsum[1] + wsum[2] + wsum[3];
    srstd = rsqrtf(tot * (1.f / H_) + EPS_);
  }
  __syncthreads();
  float r = srstd;
  int e = threadIdx.x & 15;
  int chunk = threadIdx.x >> 4;
  float s = 0.f;
  for (int c = chunk * 128; c < chunk * 128 + 128; ++c)
    s += xr[c] * r * lnw[c] * gw[c * E_ + e];
  __shared__ float red[16][16];
  red[chunk][e] = s;
  __syncthreads();
  if (threadIdx.x < 16) {
    float tot = 0.f;
    for (int c2 = 0; c2 < 16; ++c2) tot += red[c2][threadIdx.x];
    logits[(size_t)t * E_ + threadIdx.x] = tot;
  }
}

// ---------------- gating: softmax + top2 + counts ----------------
__global__ __launch_bounds__(256) void gate_topk_k(const float* __restrict__ logits,
                                                   int* __restrict__ counts,
                                                   int* __restrict__ topi,
                                                   float* __restrict__ topw) {
  int t = blockIdx.x * 256 + threadIdx.x;
  if (t >= T_) return;
  float l[E_];
  float mx = -INFINITY;
  for (int e = 0; e < E_; ++e) { l[e] = logits[t * E_ + e]; mx = fmaxf(mx, l[e]); }
  for (int e = 0; e < E_; ++e) l[e] = expf(l[e] - mx);
  int i0 = 0;
  for (int e = 1; e < E_; ++e) if (l[e] > l[i0]) i0 = e;
  int i1 = (i0 == 0) ? 1 : 0;
  for (int e = 0; e < E_; ++e) if (e != i0 && l[e] > l[i1]) i1 = e;
  float p0 = l[i0], p1 = l[i1];
  float inv = 1.f / (p0 + p1);
  topi[t * 2] = i0; topi[t * 2 + 1] = i1;
  topw[t * 2] = p0 * inv; topw[t * 2 + 1] = p1 * inv;
  atomicAdd(&counts[i0], 1);
  atomicAdd(&counts[i1], 1);
}

__global__ void make_offsets_k(const int* __restrict__ counts, int* __restrict__ offsets,
                               int* __restrict__ fill) {
  if (threadIdx.x == 0 && blockIdx.x == 0) {
    int acc = 0;
    for (int e = 0; e < E_; ++e) { offsets[e] = acc; fill[e] = acc; acc += counts[e]; }
    offsets[E_] = acc;
  }
}

__global__ __launch_bounds__(256) void scatter_k(const int* __restrict__ topi,
                                                 int* __restrict__ fill,
                                                 int* __restrict__ routed_token,
                                                 int* __restrict__ token_rows) {
  int t = blockIdx.x * 256 + threadIdx.x;
  if (t >= T_) return;
  for (int k = 0; k < 2; ++k) {
    int e = topi[t * 2 + k];
    int row = atomicAdd(&fill[e], 1);
    routed_token[row] = t;
    token_rows[t * 2 + k] = row;
  }
}

// ---------------- final combine ----------------
__global__ __launch_bounds__(256) void final_k(const float* __restrict__ resid_attn,
                                               const float* __restrict__ res_mlp,
                                               const float* __restrict__ moe_rows,
                                               const int* __restrict__ token_rows,
                                               const float* __restrict__ topw,
                                               float* __restrict__ out) {
  int idx = blockIdx.x * 256 + threadIdx.x;
  if (idx >= T_ * H_) return;
  int t = idx >> 11, c = idx & (H_ - 1);
  int r0 = token_rows[t * 2], r1 = token_rows[t * 2 + 1];
  float w0 = topw[t * 2], w1 = topw[t * 2 + 1];
  out[idx] = resid_attn[idx] + res_mlp[idx]
           + w0 * moe_rows[(size_t)r0 * H_ + c]
           + w1 * moe_rows[(size_t)r1 * H_ + c];
}

extern "C" void kernel_launch(void* const* d_in, const int* in_sizes, int n_in,
                              void* d_out, int out_size, void* d_ws, size_t ws_size,
                              hipStream_t stream) {
  const float* hidden    = (const float*)d_in[0];
  const float* ln_in_w   = (const float*)d_in[1];
  const float* ln_post_w = (const float*)d_in[2];
  const float* ln_res_w  = (const float*)d_in[3];
  const float* wqkv      = (const float*)d_in[4];
  const float* wo        = (const float*)d_in[5];
  const float* res_w13   = (const float*)d_in[6];
  const float* res_w2    = (const float*)d_in[7];
  const float* gate_w    = (const float*)d_in[8];
  const float* ws_moe    = (const float*)d_in[9];
  const float* w2s       = (const float*)d_in[10];
  float* out = (float*)d_out;

  const size_t TH = (size_t)T_ * H_;
  char* p = (char*)d_ws;
  auto alloc = [&](size_t bytes) { char* q = p; p += (bytes + 255) & ~(size_t)255; return q; };
  unsigned short* wqkv_t = (unsigned short*)alloc((size_t)QKVN * H_ * 2);
  unsigned short* wo_t   = (unsigned short*)alloc((size_t)H_ * H_ * 2);
  unsigned short* w13_t  = (unsigned short*)alloc((size_t)4096 * H_ * 2);
  unsigned short* w2_t   = (unsigned short*)alloc((size_t)H_ * H_ * 2);
  float* qkv      = (float*)alloc((size_t)T_ * QKVN * 4);   // reused as res_mlp
  float* gu       = (float*)alloc((size_t)T_ * 4096 * 4);   // reused as moe_gu
  float* moe_rows = (float*)alloc((size_t)4096 * H_ * 4);
  float* resid    = (float*)alloc(TH * 4);
  unsigned short* bfA          = (unsigned short*)alloc(TH * 2); // x_ln_in -> hmid -> moe_hmid
  unsigned short* x_ln_post_bf = (unsigned short*)alloc(TH * 2);
  unsigned short* attn_bf      = (unsigned short*)alloc(TH * 2); // attn_out -> x_ln_res
  float* logits = (float*)alloc((size_t)T_ * E_ * 4);
  float* topw   = (float*)alloc((size_t)T_ * 2 * 4);
  int* counts       = (int*)alloc(16 * 4);
  int* offsets      = (int*)alloc(24 * 4);
  int* fill         = (int*)alloc(16 * 4);
  int* topi         = (int*)alloc((size_t)T_ * 2 * 4);
  int* token_rows   = (int*)alloc((size_t)T_ * 2 * 4);
  int* routed_token = (int*)alloc((size_t)T_ * 2 * 4);
  float* res_mlp = qkv;
  float* moe_gu  = gu;

  // weight transposes (fp32 [K][N] -> bf16 [N][K])
  transp_bf_k<<<dim3(QKVN / 32, H_ / 32), 256, 0, stream>>>(wqkv, wqkv_t, H_, QKVN);
  transp_bf_k<<<dim3(H_ / 32, H_ / 32), 256, 0, stream>>>(wo, wo_t, H_, H_);
  transp_bf_k<<<dim3(4096 / 32, H_ / 32), 256, 0, stream>>>(res_w13, w13_t, H_, 4096);
  transp_bf_k<<<dim3(H_ / 32, H_ / 32), 256, 0, stream>>>(res_w2, w2_t, H_, H_);
  // rmsnorms
  rmsnorm_bf_k<<<T_, 256, 0, stream>>>(hidden, ln_in_w, bfA);
  rmsnorm_bf_k<<<T_, 256, 0, stream>>>(hidden, ln_post_w, x_ln_post_bf);
  // qkv = x_ln_in @ wqkv
  gemm_mfma_tn<<<dim3(QKVN / BN, T_ / BM), 256, 0, stream>>>(bfA, wqkv_t, qkv, T_, QKVN, H_);
  // rope + attention (MFMA flash)
  rope_k<<<(T_ * (NH_ + NKV_) * 64 + 255) / 256, 256, 0, stream>>>(qkv);
  flash_attn_mfma_k<<<dim3(NH_, T_ / 64), 256, 0, stream>>>(qkv, attn_bf);
  // attn proj -> resid; add residual
  gemm_mfma_tn<<<dim3(H_ / BN, T_ / BM), 256, 0, stream>>>(attn_bf, wo_t, resid, T_, H_, H_);
  add_k<<<(int)(TH / 256), 256, 0, stream>>>(hidden, resid, (int)TH);
  // residual MLP
  rmsnorm_bf_k<<<T_, 256, 0, stream>>>(resid, ln_res_w, attn_bf);   // x_ln_res
  gemm_mfma_tn<<<dim3(4096 / BN, T_ / BM), 256, 0, stream>>>(attn_bf, w13_t, gu, T_, 4096, H_);
  silu_mul_bf_k<<<(int)(TH / 256), 256, 0, stream>>>(gu, bfA, T_, H_);  // hmid
  gemm_mfma_tn<<<dim3(H_ / BN, T_ / BM), 256, 0, stream>>>(bfA, w2_t, res_mlp, T_, H_, H_);
  // gate + routing (fp32 logits from hidden — routing must not see bf16 rounding)
  gate_fp32_k<<<T_, 256, 0, stream>>>(hidden, ln_post_w, gate_w, logits);
  hipMemsetAsync(counts, 0, 16 * sizeof(int), stream);
  gate_topk_k<<<T_ / 256, 256, 0, stream>>>(logits, counts, topi, topw);
  make_offsets_k<<<1, 64, 0, stream>>>(counts, offsets, fill);
  scatter_k<<<T_ / 256, 256, 0, stream>>>(topi, fill, routed_token, token_rows);
  // MoE expert GEMMs (B fp32 staged -> bf16 in kernel)
  gemm_mfma_routed<<<dim3(2 * I_ / BN, 4096 / BM, E_), 256, 0, stream>>>(
      x_ln_post_bf, H_, ws_moe, moe_gu, 2 * I_, routed_token, offsets, 2 * I_, H_);
  silu_mul_bf_k<<<(int)(TH / 256), 256, 0, stream>>>(moe_gu, bfA, 2 * T_, I_);  // moe_hmid
  gemm_mfma_routed<<<dim3(H_ / BN, 4096 / BM, E_), 256, 0, stream>>>(
      bfA, I_, w2s, moe_rows, H_, nullptr, offsets, H_, I_);
  // final combine
  final_k<<<(int)(TH / 256), 256, 0, stream>>>(resid, res_mlp, moe_rows, token_rows, topw, out);
}

// Round 2
// 1162.274 us; speedup vs baseline: 1.7345x; 1.0032x over previous
//
#include <hip/hip_runtime.h>
#include <math.h>

#define T_    2048
#define H_    2048
#define NH_   16
#define NKV_  4
#define HD_   128
#define I_    1024
#define E_    16
#define QKVN  3072
#define EPS_  1e-5f

typedef __attribute__((ext_vector_type(8))) __bf16 bf16x8;
typedef __attribute__((ext_vector_type(4))) __bf16 bf16x4;
typedef __attribute__((ext_vector_type(4))) float f32x4;
typedef __attribute__((ext_vector_type(8))) unsigned short ushort8v;
typedef __attribute__((ext_vector_type(4))) unsigned short ushort4v;

__device__ __forceinline__ unsigned short f2bf(float f) {
  union { float f; unsigned u; } v; v.f = f;
  return (unsigned short)((v.u + 0x7fffu + ((v.u >> 16) & 1u)) >> 16);
}
__device__ __forceinline__ float bf2f(unsigned short h) {
  union { unsigned u; float f; } v; v.u = ((unsigned)h) << 16;
  return v.f;
}
__device__ __forceinline__ void ldsdma16(const void* g, void* l) {
  __builtin_amdgcn_global_load_lds((const __attribute__((address_space(1))) void*)g,
                                   (__attribute__((address_space(3))) void*)l, 16, 0, 0);
}

// ---------------- RMSNorm -> bf16 ----------------
__global__ __launch_bounds__(256) void rmsnorm_bf_k(const float* __restrict__ x,
                                                    const float* __restrict__ w,
                                                    unsigned short* __restrict__ out) {
  int t = blockIdx.x;
  const float* xr = x + (size_t)t * H_;
  float ss = 0.f;
  for (int c = threadIdx.x; c < H_; c += 256) { float v = xr[c]; ss += v * v; }
#pragma unroll
  for (int off = 32; off > 0; off >>= 1) ss += __shfl_xor(ss, off);
  __shared__ float wsum[4];
  __shared__ float srstd;
  int wid = threadIdx.x >> 6;
  if ((threadIdx.x & 63) == 0) wsum[wid] = ss;
  __syncthreads();
  if (threadIdx.x == 0) {
    float tot = wsum[0] + wsum[1] + wsum[2] + wsum[3];
    srstd = rsqrtf(tot * (1.f / H_) + EPS_);
  }
  __syncthreads();
  float r = srstd;
  unsigned short* orow = out + (size_t)t * H_;
  for (int c = threadIdx.x; c < H_; c += 256) orow[c] = f2bf(xr[c] * r * w[c]);
}

// ---------------- transpose + fp32->bf16:  in[K][N] -> out[N][K] ----------------
__global__ __launch_bounds__(256) void transp_bf_k(const float* __restrict__ in,
                                                   unsigned short* __restrict__ out,
                                                   int K, int N) {
  __shared__ float tile[32][33];
  int k0 = blockIdx.y * 32, n0 = blockIdx.x * 32;
  int c = threadIdx.x & 31, r = threadIdx.x >> 5;  // r: 0..7
  for (int rr = r; rr < 32; rr += 8)
    tile[rr][c] = in[(size_t)(k0 + rr) * N + n0 + c];
  __syncthreads();
  for (int rr = r; rr < 32; rr += 8)
    out[(size_t)(n0 + rr) * K + k0 + c] = f2bf(tile[c][rr]);
}

// ---------------- MFMA GEMM: C[M,N] = A[M,K](bf16) @ Bt[N,K](bf16)^T ----------------
// Split-K via blockIdx.z: if gridDim.z > 1, C must be pre-zeroed; epilogue atomicAdd.
#define BM 128
#define BN 128
#define BK 32
__global__ __launch_bounds__(256) void gemm_mfma_tn(const unsigned short* __restrict__ A,
                                                    const unsigned short* __restrict__ Bt,
                                                    float* __restrict__ C,
                                                    int M, int N, int K) {
  __shared__ unsigned short sA[BM * BK];
  __shared__ unsigned short sB[BN * BK];
  const int tid = threadIdx.x;
  const int wave = tid >> 6;
  const int lane = tid & 63;
  const int m0 = blockIdx.y * BM;
  const int n0 = blockIdx.x * BN;
  const int nz = gridDim.z;
  const int kper = K / nz;
  const int kbeg = blockIdx.z * kper;
  const int wm = (wave & 1) * 64;
  const int wn = (wave >> 1) * 64;
  const int srow = wave * 32 + (lane >> 2);
  const int sch  = (lane & 3) * 8;
  const unsigned short* ga0 = A  + (size_t)(m0 + srow) * K + kbeg + sch;
  const unsigned short* ga1 = A  + (size_t)(m0 + srow + 16) * K + kbeg + sch;
  const unsigned short* gb0 = Bt + (size_t)(n0 + srow) * K + kbeg + sch;
  const unsigned short* gb1 = Bt + (size_t)(n0 + srow + 16) * K + kbeg + sch;
  unsigned short* la0 = &sA[(wave * 32) * BK];
  unsigned short* la1 = &sA[(wave * 32 + 16) * BK];
  unsigned short* lb0 = &sB[(wave * 32) * BK];
  unsigned short* lb1 = &sB[(wave * 32 + 16) * BK];
  const int frm = lane & 15;
  const int quad = lane >> 4;
  f32x4 acc[4][4] = {};
  for (int k0 = 0; k0 < kper; k0 += BK) {
    ldsdma16(ga0, la0);
    ldsdma16(ga1, la1);
    ldsdma16(gb0, lb0);
    ldsdma16(gb1, lb1);
    ga0 += BK; ga1 += BK; gb0 += BK; gb1 += BK;
    __syncthreads();
    bf16x8 af[4], bf[4];
#pragma unroll
    for (int i = 0; i < 4; ++i) {
      af[i] = *(const bf16x8*)&sA[(wm + i * 16 + frm) * BK + quad * 8];
      bf[i] = *(const bf16x8*)&sB[(wn + i * 16 + frm) * BK + quad * 8];
    }
#pragma unroll
    for (int i = 0; i < 4; ++i)
#pragma unroll
      for (int j = 0; j < 4; ++j)
        acc[i][j] = __builtin_amdgcn_mfma_f32_16x16x32_bf16(af[i], bf[j], acc[i][j], 0, 0, 0);
    __syncthreads();
  }
  const bool single = (nz == 1);
#pragma unroll
  for (int i = 0; i < 4; ++i) {
    int rbase = m0 + wm + i * 16 + quad * 4;
#pragma unroll
    for (int j = 0; j < 4; ++j) {
      int c = n0 + wn + j * 16 + frm;
      float* cp = C + (size_t)rbase * N + c;
#pragma unroll
      for (int r = 0; r < 4; ++r) {
        if (single) cp[(size_t)r * N] = acc[i][j][r];
        else        atomicAdd(&cp[(size_t)r * N], acc[i][j][r]);
      }
    }
  }
}

// ------- routed MFMA GEMM: C[r][n] = A[gather[r]] . B_e[n][:K]; B fp32 staged->bf16 -------
__global__ __launch_bounds__(256) void gemm_mfma_routed(const unsigned short* __restrict__ A, int lda,
                                                        const float* __restrict__ B,
                                                        float* __restrict__ C, int ldc,
                                                        const int* __restrict__ gather,
                                                        const int* __restrict__ offsets,
                                                        int N, int K) {
  const int e = blockIdx.z;
  const int rs = offsets[e], re = offsets[e + 1];
  const int r0 = rs + blockIdx.y * BM;
  if (r0 >= re) return;
  const int n0 = blockIdx.x * BN;
  const float* Be = B + (size_t)e * N * K;
  __shared__ unsigned short sA[BM * BK];
  __shared__ unsigned short sB[BN * BK];
  const int tid = threadIdx.x;
  const int wave = tid >> 6;
  const int lane = tid & 63;
  const int wm = (wave & 1) * 64;
  const int wn = (wave >> 1) * 64;
  int ra0 = r0 + wave * 32 + (lane >> 2);
  int ra1 = ra0 + 16;
  int c0 = ra0 < re ? ra0 : re - 1;
  int c1 = ra1 < re ? ra1 : re - 1;
  int src0 = gather ? gather[c0] : c0;
  int src1 = gather ? gather[c1] : c1;
  const int sch = (lane & 3) * 8;
  const unsigned short* ga0 = A + (size_t)src0 * lda + sch;
  const unsigned short* ga1 = A + (size_t)src1 * lda + sch;
  unsigned short* la0 = &sA[(wave * 32) * BK];
  unsigned short* la1 = &sA[(wave * 32 + 16) * BK];
  const int brow = tid >> 1;
  const int bk = (tid & 1) * 16;
  const float* bp0 = Be + (size_t)(n0 + brow) * K + bk;
  unsigned short* bdst = &sB[brow * BK + bk];
  const int frm = lane & 15;
  const int quad = lane >> 4;
  f32x4 acc[4][4] = {};
  for (int k0 = 0; k0 < K; k0 += BK) {
    ldsdma16(ga0, la0);
    ldsdma16(ga1, la1);
    ga0 += BK; ga1 += BK;
    const float* bp = bp0 + k0;
#pragma unroll
    for (int q = 0; q < 4; ++q) {
      float4 v = *(const float4*)(bp + q * 4);
      bdst[q * 4 + 0] = f2bf(v.x);
      bdst[q * 4 + 1] = f2bf(v.y);
      bdst[q * 4 + 2] = f2bf(v.z);
      bdst[q * 4 + 3] = f2bf(v.w);
    }
    __syncthreads();
    bf16x8 af[4], bfr[4];
#pragma unroll
    for (int i = 0; i < 4; ++i) {
      af[i]  = *(const bf16x8*)&sA[(wm + i * 16 + frm) * BK + quad * 8];
      bfr[i] = *(const bf16x8*)&sB[(wn + i * 16 + frm) * BK + quad * 8];
    }
#pragma unroll
    for (int i = 0; i < 4; ++i)
#pragma unroll
      for (int j = 0; j < 4; ++j)
        acc[i][j] = __builtin_amdgcn_mfma_f32_16x16x32_bf16(af[i], bfr[j], acc[i][j], 0, 0, 0);
    __syncthreads();
  }
#pragma unroll
  for (int i = 0; i < 4; ++i) {
    int rbase = r0 + wm + i * 16 + quad * 4;
#pragma unroll
    for (int j = 0; j < 4; ++j) {
      int c = n0 + wn + j * 16 + frm;
#pragma unroll
      for (int r = 0; r < 4; ++r) {
        int rr = rbase + r;
        if (rr < re) C[(size_t)rr * ldc + c] = acc[i][j][r];
      }
    }
  }
}

// ---------------- RoPE (NeoX) in-place on q and k inside qkv ----------------
__global__ __launch_bounds__(256) void rope_k(float* __restrict__ qkv) {
  int idx = blockIdx.x * 256 + threadIdx.x;
  const int total = T_ * (NH_ + NKV_) * 64;
  if (idx >= total) return;
  int i = idx & 63;
  int head = (idx >> 6) % (NH_ + NKV_);
  int t = idx / (64 * (NH_ + NKV_));
  float* base = qkv + (size_t)t * QKVN + (head < NH_ ? head * HD_ : NH_ * HD_ + (head - NH_) * HD_);
  float inv = powf(10000.f, -(float)i * (1.f / 64.f));
  float ang = (float)t * inv;
  float c = cosf(ang), s = sinf(ang);
  float x1 = base[i], x2 = base[i + 64];
  base[i]      = x1 * c - x2 * s;
  base[i + 64] = x2 * c + x1 * s;
}

// ---------------- MFMA flash attention, split-KV ----------------
// block = 4 waves; wave w owns 16 q-rows of q-supertile qt (64 rows).
// KV chunking: chunk 0 = kv [0,1024), chunk 1 = kv [1024, 2048). Blocks write
// UNNORMALIZED partials (O~ fp32, m, l); attn_combine_k merges (1 or 2 chunks).
// blockIdx.y in [0,48) -> (qt, ch), heavy blocks (16 tiles) first.
// KV tile = 64 rows. LDS: sK[64][128] bf16 row-XOR-swizzled; sVt[128][64] bf16
// (transposed, d-row XOR-swizzled, staged by d-column threads with b128 writes);
// sP per-wave stride-72 for the P C-layout -> A-layout round-trip.
__global__ __launch_bounds__(256) void flash_attn_splitk_k(const float* __restrict__ qkv,
                                                           float* __restrict__ partO,
                                                           float* __restrict__ partML) {
  const int h = blockIdx.x;
  const int y = blockIdx.y;
  int qt, ch;
  if (y < 17)      { qt = 15 + y;        ch = 0; }   // 16-tile blocks
  else if (y < 33) { qt = 31 - (y - 17); ch = 1; }   // qt 31..16, work 16..1
  else             { qt = 14 - (y - 33); ch = 0; }   // qt 14..0, work 15..1
  const int kvh = h >> 2;
  const int tid = threadIdx.x;
  const int wave = tid >> 6, lane = tid & 63;
  const int frm = lane & 15, quad = lane >> 4;
  const int q0w = qt * 64 + wave * 16;

  __shared__ unsigned short sK[64 * 128];
  __shared__ unsigned short sVt[128 * 64];
  __shared__ unsigned short sP[4][16 * 72];

  const float scale = 0.08838834764831845f;  // 1/sqrt(128)

  // ---- hoist Q into registers: A-frag row q0w+frm, k-slice ks ----
  bf16x8 qf[4];
  {
    const float* qrow = qkv + (size_t)(q0w + frm) * QKVN + h * HD_;
#pragma unroll
    for (int ks = 0; ks < 4; ++ks) {
      float4 u = *(const float4*)(qrow + ks * 32 + quad * 8);
      float4 v = *(const float4*)(qrow + ks * 32 + quad * 8 + 4);
      union { ushort8v u; bf16x8 b; } cv;
      cv.u[0] = f2bf(u.x); cv.u[1] = f2bf(u.y); cv.u[2] = f2bf(u.z); cv.u[3] = f2bf(u.w);
      cv.u[4] = f2bf(v.x); cv.u[5] = f2bf(v.y); cv.u[6] = f2bf(v.z); cv.u[7] = f2bf(v.w);
      qf[ks] = cv.b;
    }
  }

  float m[4] = {-INFINITY, -INFINITY, -INFINITY, -INFINITY};
  float l[4] = {0.f, 0.f, 0.f, 0.f};
  f32x4 oacc[8] = {};

  const int sthr = tid & 127;
  const bool doV = tid >= 128;
  const int kt0 = ch * 16;
  const int ktend = (qt < kt0 + 15) ? qt : (kt0 + 15);

  for (int kt = kt0; kt <= ktend; ++kt) {
    const int s0 = kt * 64;
    // ---------- stage: threads 0-127 -> K rows; threads 128-255 -> V^T columns ----------
    if (doV) {
      const int d = sthr;  // 0..127, one d-column
      const float* vcol = qkv + (size_t)s0 * QKVN + (NH_ + NKV_) * HD_ + kvh * HD_ + d;
#pragma unroll
      for (int c = 0; c < 8; ++c) {
        ushort8v pk;
#pragma unroll
        for (int j = 0; j < 8; ++j) pk[j] = f2bf(vcol[(size_t)(c * 8 + j) * QKVN]);
        unsigned off = ((unsigned)(d * 128 + c * 16)) ^ (((unsigned)d & 7u) << 4);
        *(ushort8v*)((char*)sVt + off) = pk;
      }
    } else {
      const int row = sthr >> 1, half = (sthr & 1) * 64;
      const float* krow = qkv + (size_t)(s0 + row) * QKVN + NH_ * HD_ + kvh * HD_ + half;
#pragma unroll
      for (int c = 0; c < 16; ++c) {
        float4 k4 = *(const float4*)(krow + c * 4);
        ushort4v kw;
        kw[0] = f2bf(k4.x); kw[1] = f2bf(k4.y); kw[2] = f2bf(k4.z); kw[3] = f2bf(k4.w);
        unsigned off = ((unsigned)(row * 256 + half * 2 + c * 8)) ^ (((unsigned)row & 7u) << 4);
        *(ushort4v*)((char*)sK + off) = kw;
      }
    }
    __syncthreads();

    if (s0 <= q0w) {  // wave-uniform: skip fully-masked tiles
      // ---------- S = Q K^T : 4 kv-subtiles x 4 k-slices ----------
      f32x4 sacc[4] = {};
#pragma unroll
      for (int sub = 0; sub < 4; ++sub) {
        const int row = sub * 16 + frm;
        const unsigned swz = ((unsigned)row & 7u) << 4;
#pragma unroll
        for (int ks = 0; ks < 4; ++ks) {
          unsigned koff = ((unsigned)(row * 256 + ks * 64 + quad * 16)) ^ swz;
          bf16x8 kf = *(const bf16x8*)((char*)sK + koff);
          sacc[sub] = __builtin_amdgcn_mfma_f32_16x16x32_bf16(qf[ks], kf, sacc[sub], 0, 0, 0);
        }
      }
      const bool edge = (s0 + 63 > q0w);
      unsigned short* sPw = sP[wave];
      // ---------- online softmax (fp32, row stats across frm lanes) ----------
#pragma unroll
      for (int r = 0; r < 4; ++r) {
        float sv[4];
#pragma unroll
        for (int sub = 0; sub < 4; ++sub) sv[sub] = sacc[sub][r] * scale;
        const int qi = q0w + quad * 4 + r;
        if (edge) {
#pragma unroll
          for (int sub = 0; sub < 4; ++sub)
            if (s0 + sub * 16 + frm > qi) sv[sub] = -INFINITY;
        }
        float mx = fmaxf(fmaxf(sv[0], sv[1]), fmaxf(sv[2], sv[3]));
        mx = fmaxf(mx, __shfl_xor(mx, 1));
        mx = fmaxf(mx, __shfl_xor(mx, 2));
        mx = fmaxf(mx, __shfl_xor(mx, 4));
        mx = fmaxf(mx, __shfl_xor(mx, 8));
        const float mnew = fmaxf(m[r], mx);
        float p[4], rs = 0.f;
#pragma unroll
        for (int sub = 0; sub < 4; ++sub) { p[sub] = __expf(sv[sub] - mnew); rs += p[sub]; }
        rs += __shfl_xor(rs, 1);
        rs += __shfl_xor(rs, 2);
        rs += __shfl_xor(rs, 4);
        rs += __shfl_xor(rs, 8);
        const float alpha = __expf(m[r] - mnew);
        l[r] = l[r] * alpha + rs;
        m[r] = mnew;
#pragma unroll
        for (int sub = 0; sub < 4; ++sub)
          sPw[(quad * 4 + r) * 72 + sub * 16 + frm] = f2bf(p[sub]);
#pragma unroll
        for (int dt = 0; dt < 8; ++dt) oacc[dt][r] *= alpha;
      }
      // ---------- PV: O += P @ V  (P via per-wave LDS flip, V^T fragments) ----------
      bf16x8 pa[2];
#pragma unroll
      for (int ks = 0; ks < 2; ++ks)
        pa[ks] = *(const bf16x8*)&sPw[frm * 72 + ks * 32 + quad * 8];
#pragma unroll
      for (int dt = 0; dt < 8; ++dt) {
        const int drow = dt * 16 + frm;
        const unsigned swz = ((unsigned)drow & 7u) << 4;
#pragma unroll
        for (int ks = 0; ks < 2; ++ks) {
          unsigned voff = ((unsigned)(drow * 128 + ks * 64 + quad * 16)) ^ swz;
          bf16x8 vf = *(const bf16x8*)((char*)sVt + voff);
          oacc[dt] = __builtin_amdgcn_mfma_f32_16x16x32_bf16(pa[ks], vf, oacc[dt], 0, 0, 0);
        }
      }
    }
    __syncthreads();
  }

  // ---------- write unnormalized partials ----------
  const int plane = h * 2 + ch;
#pragma unroll
  for (int r = 0; r < 4; ++r) {
    const int row = q0w + quad * 4 + r;
    float* po = partO + ((size_t)plane * T_ + row) * HD_;
#pragma unroll
    for (int dt = 0; dt < 8; ++dt) po[dt * 16 + frm] = oacc[dt][r];
    if (frm == 0) {
      float* pml = partML + ((size_t)plane * T_ + row) * 2;
      pml[0] = m[r]; pml[1] = l[r];
    }
  }
}

// ---------------- combine split-KV partials -> bf16 attn out ----------------
__global__ __launch_bounds__(256) void attn_combine_k(const float* __restrict__ partO,
                                                      const float* __restrict__ partML,
                                                      unsigned short* __restrict__ out) {
  int idx = blockIdx.x * 256 + threadIdx.x;  // over NH_*T_*HD_ = 16 * 2^18
  const int d = idx & (HD_ - 1);
  const int row = (idx >> 7) & (T_ - 1);
  const int h = idx >> 18;
  const int p0 = h * 2;
  float m0 = partML[((size_t)p0 * T_ + row) * 2 + 0];
  float l0 = partML[((size_t)p0 * T_ + row) * 2 + 1];
  float o0 = partO[((size_t)p0 * T_ + row) * HD_ + d];
  float val;
  if (row < 1024) {
    val = o0 / l0;
  } else {
    float m1 = partML[((size_t)(p0 + 1) * T_ + row) * 2 + 0];
    float l1 = partML[((size_t)(p0 + 1) * T_ + row) * 2 + 1];
    float o1 = partO[((size_t)(p0 + 1) * T_ + row) * HD_ + d];
    float M = fmaxf(m0, m1);
    float w0 = __expf(m0 - M), w1 = __expf(m1 - M);
    val = (o0 * w0 + o1 * w1) / (l0 * w0 + l1 * w1);
  }
  out[(size_t)row * (NH_ * HD_) + h * HD_ + d] = f2bf(val);
}

// ---------------- elementwise ----------------
__global__ __launch_bounds__(256) void add_k(const float* __restrict__ a, float* __restrict__ b, int n) {
  int idx = blockIdx.x * 256 + threadIdx.x;
  if (idx < n) b[idx] = a[idx] + b[idx];
}

__global__ __launch_bounds__(256) void silu_mul_bf_k(const float* __restrict__ in,
                                                     unsigned short* __restrict__ out,
                                                     int rows, int n) {
  int idx = blockIdx.x * 256 + threadIdx.x;
  if (idx >= rows * n) return;
  int r = idx / n, c = idx - r * n;
  float g = in[(size_t)r * 2 * n + c];
  float u = in[(size_t)r * 2 * n + n + c];
  out[(size_t)r * n + c] = f2bf((g / (1.f + expf(-g))) * u);
}

// ---------- gate logits, full fp32 path: inline rmsnorm(hidden, ln_post_w) . gate_w ----------
// Routing is discontinuous (top-2 argmax) — must NOT see bf16-rounded inputs.
__global__ __launch_bounds__(256) void gate_fp32_k(const float* __restrict__ hidden,
                                                   const float* __restrict__ lnw,
                                                   const float* __restrict__ gw,
                                                   float* __restrict__ logits) {
  int t = blockIdx.x;
  const float* xr = hidden + (size_t)t * H_;
  float ss = 0.f;
  for (int c = threadIdx.x; c < H_; c += 256) { float v = xr[c]; ss += v * v; }
#pragma unroll
  for (int off = 32; off > 0; off >>= 1) ss += __shfl_xor(ss, off);
  __shared__ float wsum[4];
  __shared__ float srstd;
  int wid = threadIdx.x >> 6;
  if ((threadIdx.x & 63) == 0) wsum[wid] = ss;
  __syncthreads();
  if (threadIdx.x == 0) {
    float tot = wsum[0] + wsum[1] + wsum[2] + wsum[3];
    srstd = rsqrtf(tot * (1.f / H_) + EPS_);
  }
  __syncthreads();
  float r = srstd;
  int e = threadIdx.x & 15;
  int chunk = threadIdx.x >> 4;
  float s = 0.f;
  for (int c = chunk * 128; c < chunk * 128 + 128; ++c)
    s += xr[c] * r * lnw[c] * gw[c * E_ + e];
  __shared__ float red[16][16];
  red[chunk][e] = s;
  __syncthreads();
  if (threadIdx.x < 16) {
    float tot = 0.f;
    for (int c2 = 0; c2 < 16; ++c2) tot += red[c2][threadIdx.x];
    logits[(size_t)t * E_ + threadIdx.x] = tot;
  }
}

// ---------------- gating: softmax + top2 + counts ----------------
__global__ __launch_bounds__(256) void gate_topk_k(const float* __restrict__ logits,
                                                   int* __restrict__ counts,
                                                   int* __restrict__ topi,
                                                   float* __restrict__ topw) {
  int t = blockIdx.x * 256 + threadIdx.x;
  if (t >= T_) return;
  float l[E_];
  float mx = -INFINITY;
  for (int e = 0; e < E_; ++e) { l[e] = logits[t * E_ + e]; mx = fmaxf(mx, l[e]); }
  for (int e = 0; e < E_; ++e) l[e] = expf(l[e] - mx);
  int i0 = 0;
  for (int e = 1; e < E_; ++e) if (l[e] > l[i0]) i0 = e;
  int i1 = (i0 == 0) ? 1 : 0;
  for (int e = 0; e < E_; ++e) if (e != i0 && l[e] > l[i1]) i1 = e;
  float p0 = l[i0], p1 = l[i1];
  float inv = 1.f / (p0 + p1);
  topi[t * 2] = i0; topi[t * 2 + 1] = i1;
  topw[t * 2] = p0 * inv; topw[t * 2 + 1] = p1 * inv;
  atomicAdd(&counts[i0], 1);
  atomicAdd(&counts[i1], 1);
}

__global__ void make_offsets_k(const int* __restrict__ counts, int* __restrict__ offsets,
                               int* __restrict__ fill) {
  if (threadIdx.x == 0 && blockIdx.x == 0) {
    int acc = 0;
    for (int e = 0; e < E_; ++e) { offsets[e] = acc; fill[e] = acc; acc += counts[e]; }
    offsets[E_] = acc;
  }
}

__global__ __launch_bounds__(256) void scatter_k(const int* __restrict__ topi,
                                                 int* __restrict__ fill,
                                                 int* __restrict__ routed_token,
                                                 int* __restrict__ token_rows) {
  int t = blockIdx.x * 256 + threadIdx.x;
  if (t >= T_) return;
  for (int k = 0; k < 2; ++k) {
    int e = topi[t * 2 + k];
    int row = atomicAdd(&fill[e], 1);
    routed_token[row] = t;
    token_rows[t * 2 + k] = row;
  }
}

// ---------------- final combine ----------------
__global__ __launch_bounds__(256) void final_k(const float* __restrict__ resid_attn,
                                               const float* __restrict__ res_mlp,
                                               const float* __restrict__ moe_rows,
                                               const int* __restrict__ token_rows,
                                               const float* __restrict__ topw,
                                               float* __restrict__ out) {
  int idx = blockIdx.x * 256 + threadIdx.x;
  if (idx >= T_ * H_) return;
  int t = idx >> 11, c = idx & (H_ - 1);
  int r0 = token_rows[t * 2], r1 = token_rows[t * 2 + 1];
  float w0 = topw[t * 2], w1 = topw[t * 2 + 1];
  out[idx] = resid_attn[idx] + res_mlp[idx]
           + w0 * moe_rows[(size_t)r0 * H_ + c]
           + w1 * moe_rows[(size_t)r1 * H_ + c];
}

extern "C" void kernel_launch(void* const* d_in, const int* in_sizes, int n_in,
                              void* d_out, int out_size, void* d_ws, size_t ws_size,
                              hipStream_t stream) {
  const float* hidden    = (const float*)d_in[0];
  const float* ln_in_w   = (const float*)d_in[1];
  const float* ln_post_w = (const float*)d_in[2];
  const float* ln_res_w  = (const float*)d_in[3];
  const float* wqkv      = (const float*)d_in[4];
  const float* wo        = (const float*)d_in[5];
  const float* res_w13   = (const float*)d_in[6];
  const float* res_w2    = (const float*)d_in[7];
  const float* gate_w    = (const float*)d_in[8];
  const float* ws_moe    = (const float*)d_in[9];
  const float* w2s       = (const float*)d_in[10];
  float* out = (float*)d_out;

  const size_t TH = (size_t)T_ * H_;
  char* p = (char*)d_ws;
  auto alloc = [&](size_t bytes) { char* q = p; p += (bytes + 255) & ~(size_t)255; return q; };
  unsigned short* wqkv_t = (unsigned short*)alloc((size_t)QKVN * H_ * 2);
  unsigned short* wo_t   = (unsigned short*)alloc((size_t)H_ * H_ * 2);
  unsigned short* w13_t  = (unsigned short*)alloc((size_t)4096 * H_ * 2);
  unsigned short* w2_t   = (unsigned short*)alloc((size_t)H_ * H_ * 2);
  float* qkv      = (float*)alloc((size_t)T_ * QKVN * 4);   // reused as res_mlp
  float* gu       = (float*)alloc((size_t)T_ * 4096 * 4);   // reused as attn partO, moe_gu
  float* moe_rows = (float*)alloc((size_t)4096 * H_ * 4);   // reused as attn partML
  float* resid    = (float*)alloc(TH * 4);
  unsigned short* bfA          = (unsigned short*)alloc(TH * 2); // x_ln_in -> hmid -> moe_hmid
  unsigned short* x_ln_post_bf = (unsigned short*)alloc(TH * 2);
  unsigned short* attn_bf      = (unsigned short*)alloc(TH * 2); // attn_out -> x_ln_res
  float* logits = (float*)alloc((size_t)T_ * E_ * 4);
  float* topw   = (float*)alloc((size_t)T_ * 2 * 4);
  int* counts       = (int*)alloc(16 * 4);
  int* offsets      = (int*)alloc(24 * 4);
  int* fill         = (int*)alloc(16 * 4);
  int* topi         = (int*)alloc((size_t)T_ * 2 * 4);
  int* token_rows   = (int*)alloc((size_t)T_ * 2 * 4);
  int* routed_token = (int*)alloc((size_t)T_ * 2 * 4);
  float* res_mlp = qkv;
  float* moe_gu  = gu;
  float* partO   = gu;          // 32 planes x 2048 x 128 fp32 = 32 MB (exact fit)
  float* partML  = moe_rows;    // 32 planes x 2048 x 2 fp32 = 512 KB

  // weight transposes (fp32 [K][N] -> bf16 [N][K])
  transp_bf_k<<<dim3(QKVN / 32, H_ / 32), 256, 0, stream>>>(wqkv, wqkv_t, H_, QKVN);
  transp_bf_k<<<dim3(H_ / 32, H_ / 32), 256, 0, stream>>>(wo, wo_t, H_, H_);
  transp_bf_k<<<dim3(4096 / 32, H_ / 32), 256, 0, stream>>>(res_w13, w13_t, H_, 4096);
  transp_bf_k<<<dim3(H_ / 32, H_ / 32), 256, 0, stream>>>(res_w2, w2_t, H_, H_);
  // rmsnorms
  rmsnorm_bf_k<<<T_, 256, 0, stream>>>(hidden, ln_in_w, bfA);
  rmsnorm_bf_k<<<T_, 256, 0, stream>>>(hidden, ln_post_w, x_ln_post_bf);
  // qkv = x_ln_in @ wqkv  (split-K=2 -> 768 blocks)
  hipMemsetAsync(qkv, 0, (size_t)T_ * QKVN * 4, stream);
  gemm_mfma_tn<<<dim3(QKVN / BN, T_ / BM, 2), 256, 0, stream>>>(bfA, wqkv_t, qkv, T_, QKVN, H_);
  // rope + attention (split-KV MFMA flash + combine)
  rope_k<<<(T_ * (NH_ + NKV_) * 64 + 255) / 256, 256, 0, stream>>>(qkv);
  flash_attn_splitk_k<<<dim3(NH_, 48), 256, 0, stream>>>(qkv, partO, partML);
  attn_combine_k<<<(NH_ * T_ * HD_) / 256, 256, 0, stream>>>(partO, partML, attn_bf);
  // attn proj -> resid; add residual  (split-K=2 -> 512 blocks)
  hipMemsetAsync(resid, 0, TH * 4, stream);
  gemm_mfma_tn<<<dim3(H_ / BN, T_ / BM, 2), 256, 0, stream>>>(attn_bf, wo_t, resid, T_, H_, H_);
  add_k<<<(int)(TH / 256), 256, 0, stream>>>(hidden, resid, (int)TH);
  // residual MLP
  rmsnorm_bf_k<<<T_, 256, 0, stream>>>(resid, ln_res_w, attn_bf);   // x_ln_res
  hipMemsetAsync(gu, 0, (size_t)T_ * 4096 * 4, stream);
  gemm_mfma_tn<<<dim3(4096 / BN, T_ / BM, 2), 256, 0, stream>>>(attn_bf, w13_t, gu, T_, 4096, H_);
  silu_mul_bf_k<<<(int)(TH / 256), 256, 0, stream>>>(gu, bfA, T_, H_);  // hmid
  hipMemsetAsync(res_mlp, 0, TH * 4, stream);
  gemm_mfma_tn<<<dim3(H_ / BN, T_ / BM, 2), 256, 0, stream>>>(bfA, w2_t, res_mlp, T_, H_, H_);
  // gate + routing (fp32 logits from hidden — routing must not see bf16 rounding)
  gate_fp32_k<<<T_, 256, 0, stream>>>(hidden, ln_post_w, gate_w, logits);
  hipMemsetAsync(counts, 0, 16 * sizeof(int), stream);
  gate_topk_k<<<T_ / 256, 256, 0, stream>>>(logits, counts, topi, topw);
  make_offsets_k<<<1, 64, 0, stream>>>(counts, offsets, fill);
  scatter_k<<<T_ / 256, 256, 0, stream>>>(topi, fill, routed_token, token_rows);
  // MoE expert GEMMs (B fp32 staged -> bf16 in kernel)
  gemm_mfma_routed<<<dim3(2 * I_ / BN, 4096 / BM, E_), 256, 0, stream>>>(
      x_ln_post_bf, H_, ws_moe, moe_gu, 2 * I_, routed_token, offsets, 2 * I_, H_);
  silu_mul_bf_k<<<(int)(TH / 256), 256, 0, stream>>>(moe_gu, bfA, 2 * T_, I_);  // moe_hmid
  gemm_mfma_routed<<<dim3(H_ / BN, 4096 / BM, E_), 256, 0, stream>>>(
      bfA, I_, w2s, moe_rows, H_, nullptr, offsets, H_, I_);
  // final combine
  final_k<<<(int)(TH / 256), 256, 0, stream>>>(resid, res_mlp, moe_rows, token_rows, topw, out);
}